// Round 6
// baseline (291.442 us; speedup 1.0000x reference)
//
#include <hip/hip_runtime.h>
#include <float.h>

#define NT 32768
#define DIM 2048
#define NE 64
#define KSPLIT 2
#define KW (DIM / KSPLIT)    // 1024 k per wave
#define TPB 64               // tokens per block

typedef __attribute__((ext_vector_type(8))) float f8v;

// wt8[eq][k][j] = gw[eq*8 + j][k]  (512 KB), coalesced both phases via LDS tile
__global__ __launch_bounds__(256)
void transpose_w(const float* __restrict__ gw, float* __restrict__ wt) {
    __shared__ float ls[64][65];
    const int k0 = blockIdx.x * 64;
    const int r  = threadIdx.x >> 2;          // load: expert; store: local k
    const int c0 = (threadIdx.x & 3) * 16;
#pragma unroll
    for (int j = 0; j < 16; j += 4) {
        float4 v = *(const float4*)(gw + (size_t)r * DIM + k0 + c0 + j);
        ls[r][c0 + j]     = v.x;
        ls[r][c0 + j + 1] = v.y;
        ls[r][c0 + j + 2] = v.z;
        ls[r][c0 + j + 3] = v.w;
    }
    __syncthreads();
    // this thread stores k = k0 + r, experts c0..c0+15 (= eq quarters c0/8, c0/8+1)
    float* d0 = wt + ((size_t)(c0 >> 3) * DIM + (k0 + r)) * 8;
    float* d1 = d0 + (size_t)DIM * 8;
    *(float4*)(d0)     = make_float4(ls[c0+0][r],  ls[c0+1][r],  ls[c0+2][r],  ls[c0+3][r]);
    *(float4*)(d0 + 4) = make_float4(ls[c0+4][r],  ls[c0+5][r],  ls[c0+6][r],  ls[c0+7][r]);
    *(float4*)(d1)     = make_float4(ls[c0+8][r],  ls[c0+9][r],  ls[c0+10][r], ls[c0+11][r]);
    *(float4*)(d1 + 4) = make_float4(ls[c0+12][r], ls[c0+13][r], ls[c0+14][r], ls[c0+15][r]);
}

__global__ __launch_bounds__(1024, 8)
void router_main(const float* __restrict__ x, const float* __restrict__ wt,
                 float* __restrict__ out) {
    __shared__ float red[KSPLIT][TPB][NE];   // 32 KB, cols XOR-swizzled per row

    const int tid  = threadIdx.x;
    const int lane = tid & 63;                               // lane == local token
    const int wid  = __builtin_amdgcn_readfirstlane(tid >> 6);
    const int eq   = wid & 7;                                // 8-expert group
    const int kh   = wid >> 3;                               // k-half 0..1
    const int tblk = blockIdx.x * TPB;

    float acc[8];
#pragma unroll
    for (int e = 0; e < 8; ++e) acc[e] = 0.f;

    const float* xp = x + (size_t)(tblk + lane) * DIM + kh * KW;
    const float* wp = wt + ((size_t)eq * DIM + (size_t)kh * KW) * 8;  // uniform

    float4 xa = *(const float4*)(xp);
    float4 xb = *(const float4*)(xp + 4);

    for (int kg = 0; kg < KW; kg += 8) {
        float4 xc = make_float4(0.f, 0.f, 0.f, 0.f);
        float4 xd = make_float4(0.f, 0.f, 0.f, 0.f);
        if (kg + 8 < KW) {
            xc = *(const float4*)(xp + kg + 8);
            xd = *(const float4*)(xp + kg + 12);
        }
        // batch: 8 k-steps' w = 8 x s_load_dwordx8 (uniform), ONE drain, 64 FMAs
        const float* wk = wp + (size_t)kg * 8;
        const f8v a0 = *(const f8v*)(wk);
        const f8v a1 = *(const f8v*)(wk + 8);
        const f8v a2 = *(const f8v*)(wk + 16);
        const f8v a3 = *(const f8v*)(wk + 24);
        const f8v a4 = *(const f8v*)(wk + 32);
        const f8v a5 = *(const f8v*)(wk + 40);
        const f8v a6 = *(const f8v*)(wk + 48);
        const f8v a7 = *(const f8v*)(wk + 56);
#pragma unroll
        for (int e = 0; e < 8; ++e) {
            acc[e] = fmaf(a0[e], xa.x, acc[e]);
            acc[e] = fmaf(a1[e], xa.y, acc[e]);
            acc[e] = fmaf(a2[e], xa.z, acc[e]);
            acc[e] = fmaf(a3[e], xa.w, acc[e]);
            acc[e] = fmaf(a4[e], xb.x, acc[e]);
            acc[e] = fmaf(a5[e], xb.y, acc[e]);
            acc[e] = fmaf(a6[e], xb.z, acc[e]);
            acc[e] = fmaf(a7[e], xb.w, acc[e]);
        }
        xa = xc; xb = xd;
    }

    // deposit partials: wave (kh,eq) owns cols eq*8..eq*8+7, XOR-swizzled (2-way = free)
    const int swz = (lane & 7) << 2;
    *(float4*)&red[kh][lane][(eq * 8)     ^ swz] =
        make_float4(acc[0], acc[1], acc[2], acc[3]);
    *(float4*)&red[kh][lane][(eq * 8 + 4) ^ swz] =
        make_float4(acc[4], acc[5], acc[6], acc[7]);
    __syncthreads();

    // ---- epilogue: 16 threads per token, 4 experts each ----
    float* mout = out;                               // (NT,64) mask
    float* wout = out + (size_t)NT * NE;             // (NT,2) weights
    float* iout = wout + (size_t)NT * 2;             // (NT,2) indices (as float)

    const int t   = tid >> 4;                        // local token 0..63
    const int s   = tid & 15;                        // 4-expert segment
    const int tok = tblk + t;
    const int col = (s * 4) ^ ((t & 7) << 2);

    float4 p0 = *(const float4*)&red[0][t][col];
    float4 p1 = *(const float4*)&red[1][t][col];
    float v0 = p0.x + p1.x, v1 = p0.y + p1.y, v2 = p0.z + p1.z, v3 = p0.w + p1.w;

    // local top-2 over 4 (ascending e, strict > keeps lowest index on ties)
    float m1 = -FLT_MAX, m2 = -FLT_MAX; int i1 = NE, i2 = NE;
    {
        float vv[4] = {v0, v1, v2, v3};
#pragma unroll
        for (int j = 0; j < 4; ++j) {
            float val = vv[j]; int e = s * 4 + j;
            if (val > m1)      { m2 = m1; i2 = i1; m1 = val; i1 = e; }
            else if (val > m2) { m2 = val; i2 = e; }
        }
    }
    // merge across the 16 threads of this token (same wave)
#pragma unroll
    for (int off = 1; off <= 8; off <<= 1) {
        float om1 = __shfl_xor(m1, off, 64);
        int   oi1 = __shfl_xor(i1, off, 64);
        float om2 = __shfl_xor(m2, off, 64);
        int   oi2 = __shfl_xor(i2, off, 64);
        bool selfFirst = (m1 > om1) || (m1 == om1 && i1 < oi1);
        if (selfFirst) {
            bool keep = (m2 > om1) || (m2 == om1 && i2 < oi1);
            if (!keep) { m2 = om1; i2 = oi1; }
        } else {
            bool c = (m1 > om2) || (m1 == om2 && i1 < oi2);
            if (c) { m2 = m1; i2 = i1; } else { m2 = om2; i2 = oi2; }
            m1 = om1; i1 = oi1;
        }
    }

    float ed  = expf(m2 - m1);
    float inv = 1.f / (1.f + ed);

    // mask: each thread writes its 4-expert float4
    float4 mv;
    mv.x = (s * 4     == i1 || s * 4     == i2) ? 1.f : 0.f;
    mv.y = (s * 4 + 1 == i1 || s * 4 + 1 == i2) ? 1.f : 0.f;
    mv.z = (s * 4 + 2 == i1 || s * 4 + 2 == i2) ? 1.f : 0.f;
    mv.w = (s * 4 + 3 == i1 || s * 4 + 3 == i2) ? 1.f : 0.f;
    *(float4*)(mout + (size_t)tok * NE + s * 4) = mv;

    if (s == 0) {
        *(float2*)(wout + 2 * tok) = make_float2(inv, ed * inv);
        *(float2*)(iout + 2 * tok) = make_float2((float)i1, (float)i2);
    }
}

extern "C" void kernel_launch(void* const* d_in, const int* in_sizes, int n_in,
                              void* d_out, int out_size, void* d_ws, size_t ws_size,
                              hipStream_t stream) {
    const float* x  = (const float*)d_in[0];
    const float* gw = (const float*)d_in[1];
    float* out = (float*)d_out;
    float* wt  = (float*)d_ws;                 // 512 KB transposed weights

    transpose_w<<<dim3(DIM / 64), dim3(256), 0, stream>>>(gw, wt);
    router_main<<<dim3(NT / TPB), dim3(1024), 0, stream>>>(x, wt, out);
}

// Round 7
// 202.052 us; speedup vs baseline: 1.4424x; 1.4424x over previous
//
#include <hip/hip_runtime.h>
#include <float.h>

#define NT 32768
#define DIM 2048
#define NE 64
#define TAU 1e-3f

typedef __attribute__((ext_vector_type(8))) short short8;
typedef __attribute__((ext_vector_type(4))) float f32x4;

__device__ __forceinline__ unsigned short f2bf(float f) {
    unsigned u = __float_as_uint(f);
    u += 0x7fffu + ((u >> 16) & 1u);          // RNE
    return (unsigned short)(u >> 16);
}
__device__ __forceinline__ float bf2f(unsigned short h) {
    return __uint_as_float(((unsigned)h) << 16);
}

// Split gw into hi/lo bf16 planes (row-major [64][2048]); zero the flag counter.
__global__ __launch_bounds__(256)
void prep_w(const float* __restrict__ gw, unsigned short* __restrict__ wh,
            unsigned short* __restrict__ wl, int* __restrict__ cnt) {
    int i = (blockIdx.x * 256 + threadIdx.x) * 4;
    float4 v = *(const float4*)(gw + i);
    unsigned short h0 = f2bf(v.x), h1 = f2bf(v.y), h2 = f2bf(v.z), h3 = f2bf(v.w);
    *(ushort4*)(wh + i) = make_ushort4(h0, h1, h2, h3);
    *(ushort4*)(wl + i) = make_ushort4(f2bf(v.x - bf2f(h0)), f2bf(v.y - bf2f(h1)),
                                       f2bf(v.z - bf2f(h2)), f2bf(v.w - bf2f(h3)));
    if (blockIdx.x == 0 && threadIdx.x == 0) *cnt = 0;
}

__global__ __launch_bounds__(256, 1)
void router_mfma(const float* __restrict__ x,
                 const unsigned short* __restrict__ wh,
                 const unsigned short* __restrict__ wl,
                 float* __restrict__ out,
                 int* __restrict__ cnt, int* __restrict__ list) {
    const int tid  = threadIdx.x;
    const int lane = tid & 63;
    const int wid  = tid >> 6;
    const int t0   = blockIdx.x * 64 + wid * 16;   // 16 tokens per wave
    const int sub  = lane & 15;
    const int kg   = lane >> 4;                     // k-octet group

    const float* xp = x + (size_t)(t0 + sub) * DIM + kg * 8;
    const unsigned short* whp = wh + (size_t)sub * DIM + kg * 8;
    const unsigned short* wlp = wl + (size_t)sub * DIM + kg * 8;

    f32x4 acc[4];
#pragma unroll
    for (int et = 0; et < 4; ++et)
#pragma unroll
        for (int j = 0; j < 4; ++j) acc[et][j] = 0.f;

    float4 xb[2][8];      // chunk double buffer: 4 k-steps x 8 floats/lane
    short8 wf[2][8];      // w frags: [step parity][et*2 + (hi/lo)]

#define LOADX(buf, kc_) \
    { _Pragma("unroll") for (int s_ = 0; s_ < 4; ++s_) { \
        xb[buf][2*s_]   = *(const float4*)(xp + (kc_)*128 + s_*32); \
        xb[buf][2*s_+1] = *(const float4*)(xp + (kc_)*128 + s_*32 + 4); } }

#define LOADW(p, ks_) \
    { _Pragma("unroll") for (int et_ = 0; et_ < 4; ++et_) { \
        wf[p][2*et_]   = *(const short8*)(whp + (size_t)et_*16*DIM + (ks_)*32); \
        wf[p][2*et_+1] = *(const short8*)(wlp + (size_t)et_*16*DIM + (ks_)*32); } }

    LOADX(0, 0)
    LOADW(0, 0)

#pragma unroll 2
    for (int kc = 0; kc < 16; ++kc) {
        if (kc + 1 < 16) LOADX((kc + 1) & 1, kc + 1)   // prefetch next x chunk
#pragma unroll
        for (int s = 0; s < 4; ++s) {
            const int ks = kc * 4 + s;
            if (ks + 1 < 64) LOADW((s + 1) & 1, ks + 1)  // prefetch next w frags
            float4 a0 = xb[kc & 1][2 * s], a1 = xb[kc & 1][2 * s + 1];
            float xf[8] = {a0.x, a0.y, a0.z, a0.w, a1.x, a1.y, a1.z, a1.w};
            short8 ah, al;
#pragma unroll
            for (int j = 0; j < 8; ++j) {
                unsigned short h = f2bf(xf[j]);
                ah[j] = (short)h;
                al[j] = (short)f2bf(xf[j] - bf2f(h));
            }
#pragma unroll
            for (int et = 0; et < 4; ++et) {
                acc[et] = __builtin_amdgcn_mfma_f32_16x16x32_bf16(ah, wf[s & 1][2*et],   acc[et], 0, 0, 0);
                acc[et] = __builtin_amdgcn_mfma_f32_16x16x32_bf16(ah, wf[s & 1][2*et+1], acc[et], 0, 0, 0);
                acc[et] = __builtin_amdgcn_mfma_f32_16x16x32_bf16(al, wf[s & 1][2*et],   acc[et], 0, 0, 0);
            }
        }
    }
#undef LOADX
#undef LOADW

    // ---- epilogue: D layout col=lane&15 (expert-in-tile), row=(lane>>4)*4+r (token) ----
    float* mout = out;
    float* wout = out + (size_t)NT * NE;
    float* iout = wout + (size_t)NT * 2;

#pragma unroll
    for (int r = 0; r < 4; ++r) {
        const int tok = t0 + kg * 4 + r;
        float m1 = -FLT_MAX, m2 = -FLT_MAX, m3 = -FLT_MAX;
        int   i1 = NE, i2 = NE, i3 = NE;
        auto ins = [&](float v, int e) {
            bool b1 = (v > m1) || (v == m1 && e < i1);
            bool b2 = (v > m2) || (v == m2 && e < i2);
            bool b3 = (v > m3) || (v == m3 && e < i3);
            if (b1)      { m3 = m2; i3 = i2; m2 = m1; i2 = i1; m1 = v; i1 = e; }
            else if (b2) { m3 = m2; i3 = i2; m2 = v; i2 = e; }
            else if (b3) { m3 = v; i3 = e; }
        };
        ins(acc[0][r], sub);
        ins(acc[1][r], 16 + sub);
        ins(acc[2][r], 32 + sub);
        ins(acc[3][r], 48 + sub);
#pragma unroll
        for (int off = 1; off <= 8; off <<= 1) {   // merge across 16-lane group
            float om1 = __shfl_xor(m1, off, 64); int oi1 = __shfl_xor(i1, off, 64);
            float om2 = __shfl_xor(m2, off, 64); int oi2 = __shfl_xor(i2, off, 64);
            float om3 = __shfl_xor(m3, off, 64); int oi3 = __shfl_xor(i3, off, 64);
            ins(om1, oi1); ins(om2, oi2); ins(om3, oi3);
        }

        float ed  = expf(m2 - m1);
        float inv = 1.f / (1.f + ed);

#pragma unroll
        for (int et = 0; et < 4; ++et) {
            int e = et * 16 + sub;
            mout[(size_t)tok * NE + e] = (e == i1 || e == i2) ? 1.f : 0.f;
        }
        if (sub == 0) {
            *(float2*)(wout + 2 * tok) = make_float2(inv, ed * inv);
            *(float2*)(iout + 2 * tok) = make_float2((float)i1, (float)i2);
            if ((m1 - m2 < TAU) || (m2 - m3 < TAU)) {
                int slot = atomicAdd(cnt, 1);
                list[slot] = tok;
            }
        }
    }
}

// Exact fp32 recompute of flagged (near-tie) tokens; overwrites their outputs.
__global__ __launch_bounds__(256)
void repair(const float* __restrict__ x, const float* __restrict__ gw,
            float* __restrict__ out, const int* __restrict__ cnt,
            const int* __restrict__ list) {
    __shared__ float red[64][5];
    const int n   = *cnt;
    const int tid = threadIdx.x;
    const int e   = tid & 63, q = tid >> 6;     // expert, k-quarter

    float* mout = out;
    float* wout = out + (size_t)NT * NE;
    float* iout = wout + (size_t)NT * 2;

    for (int i = blockIdx.x; i < n; i += gridDim.x) {
        const int tok = list[i];
        const float* xr = x + (size_t)tok * DIM + q * 512;
        const float* wr = gw + (size_t)e * DIM + q * 512;
        float a = 0.f;
        for (int j = 0; j < 512; j += 4) {
            float4 xv = *(const float4*)(xr + j);
            float4 wv = *(const float4*)(wr + j);
            a = fmaf(xv.x, wv.x, a); a = fmaf(xv.y, wv.y, a);
            a = fmaf(xv.z, wv.z, a); a = fmaf(xv.w, wv.w, a);
        }
        red[e][q] = a;
        __syncthreads();
        if (tid < 64) {
            float v = ((red[e][0] + red[e][1]) + red[e][2]) + red[e][3];
            float m1 = v, m2 = -FLT_MAX; int i1 = e, i2 = NE;
#pragma unroll
            for (int off = 1; off <= 32; off <<= 1) {
                float om1 = __shfl_xor(m1, off, 64); int oi1 = __shfl_xor(i1, off, 64);
                float om2 = __shfl_xor(m2, off, 64); int oi2 = __shfl_xor(i2, off, 64);
                bool selfFirst = (m1 > om1) || (m1 == om1 && i1 < oi1);
                if (selfFirst) {
                    if (!((m2 > om1) || (m2 == om1 && i2 < oi1))) { m2 = om1; i2 = oi1; }
                } else {
                    bool c = (m1 > om2) || (m1 == om2 && i1 < oi2);
                    if (c) { m2 = m1; i2 = i1; } else { m2 = om2; i2 = oi2; }
                    m1 = om1; i1 = oi1;
                }
            }
            float ed  = expf(m2 - m1);
            float inv = 1.f / (1.f + ed);
            mout[(size_t)tok * NE + e] = (e == i1 || e == i2) ? 1.f : 0.f;
            if (e == 0) {
                *(float2*)(wout + 2 * tok) = make_float2(inv, ed * inv);
                *(float2*)(iout + 2 * tok) = make_float2((float)i1, (float)i2);
            }
        }
        __syncthreads();
    }
}

extern "C" void kernel_launch(void* const* d_in, const int* in_sizes, int n_in,
                              void* d_out, int out_size, void* d_ws, size_t ws_size,
                              hipStream_t stream) {
    const float* x  = (const float*)d_in[0];
    const float* gw = (const float*)d_in[1];
    float* out = (float*)d_out;

    unsigned short* wh = (unsigned short*)d_ws;          // 256 KB
    unsigned short* wl = wh + (size_t)NE * DIM;          // 256 KB
    int* cnt  = (int*)(wl + (size_t)NE * DIM);           // 4 B
    int* list = cnt + 1;                                 // 128 KB

    prep_w<<<dim3(128), dim3(256), 0, stream>>>(gw, wh, wl, cnt);
    router_mfma<<<dim3(NT / 64), dim3(256), 0, stream>>>(x, wh, wl, out, cnt, list);
    repair<<<dim3(256), dim3(256), 0, stream>>>(x, gw, out, cnt, list);
}